// Round 5
// baseline (895.828 us; speedup 1.0000x reference)
//
#include <hip/hip_runtime.h>

typedef __attribute__((ext_vector_type(8))) short bf16x8;
typedef __attribute__((ext_vector_type(4))) float f32x4;
typedef __attribute__((ext_vector_type(4))) unsigned short u16x4;

#define HW_ 16384
#define LDSTR 144     // 72 bf16 elems * 2B per LDS row
#define TILEB 9216    // one 64-pixel x 64-channel bf16 tile

__device__ __forceinline__ float bf2f(unsigned short u) {
  union { unsigned u; float f; } x; x.u = ((unsigned)u) << 16; return x.f;
}
__device__ __forceinline__ unsigned short f2bf(float f) {
  union { float f; unsigned u; } x; x.f = f;
  unsigned r = x.u + 0x7fffu + ((x.u >> 16) & 1u);
  return (unsigned short)(r >> 16);
}
// XOR-swizzled LDS byte offset for transposed tile xT[p][c]
__device__ __forceinline__ int swz(int row, int cb) {
  return row * LDSTR + (cb ^ (((row >> 3) & 7) << 4));
}

#define MFMA(a, b, c) __builtin_amdgcn_mfma_f32_16x16x32_bf16(a, b, c, 0, 0, 0)

__global__ __launch_bounds__(256, 4) void gci_kernel(
    const float* __restrict__ x1, const float* __restrict__ x2,
    const float* __restrict__ x3, const float* __restrict__ x4,
    const float* __restrict__ wI, const float* __restrict__ bI,
    const float* __restrict__ wS, const float* __restrict__ bS,
    const float* __restrict__ wG, const float* __restrict__ bG,
    float* __restrict__ out)
{
  // 4 tiles of [64 pixels][72 bf16]: xT0..xT3  (36864 B -> 4 blocks/CU)
  __shared__ __align__(16) char ldsb[4 * TILEB];

  const int t    = threadIdx.x;
  const int lane = t & 63;
  const int w    = t >> 6;
  const int lr   = lane & 15;
  const int lg   = lane >> 4;

  const int pix0 = blockIdx.x * 64;
  const int b    = pix0 >> 14;          // image index (HW = 16384)
  const int pimg = pix0 & (HW_ - 1);    // pixel offset within image

  const float* xin[4] = {x1, x2, x3, x4};

  // ---------- stage x1..x4 transposed (bf16) into LDS ----------
  #pragma unroll
  for (int ch2 = 0; ch2 < 4; ++ch2) {
    const int q  = ch2 * 256 + t;       // 1024 chunks: 64 channels x 16 pixel-quads
    const int c  = q >> 4;
    const int p4 = q & 15;
    const int goff = (b * 64 + c) * HW_ + pimg + p4 * 4;
    #pragma unroll
    for (int i = 0; i < 4; ++i) {
      f32x4 v = *reinterpret_cast<const f32x4*>(xin[i] + goff);
      #pragma unroll
      for (int j = 0; j < 4; ++j)
        *(unsigned short*)(ldsb + i * TILEB + swz(p4 * 4 + j, c * 2)) = f2bf(v[j]);
    }
  }

  // ---------- per-wave weight A-fragments (fp32 global -> bf16 frags) ----------
  // A-frag(m,kk): lane holds W[m*16 + (l&15)][kk*32 + (l>>4)*8 + j], j=0..7
  bf16x8 fWi[4][2], fD[4][2], fG1[4][2], fG2[4][2];
  #pragma unroll
  for (int m = 0; m < 4; ++m) {
    #pragma unroll
    for (int kk = 0; kk < 2; ++kk) {
      const int row = m * 16 + lr, col = kk * 32 + lg * 8;
      f32x4 wa = *reinterpret_cast<const f32x4*>(wI + row * 64 + col);
      f32x4 wb = *reinterpret_cast<const f32x4*>(wI + row * 64 + col + 4);
      f32x4 sa = *reinterpret_cast<const f32x4*>(wS + row * 64 + col);
      f32x4 sb = *reinterpret_cast<const f32x4*>(wS + row * 64 + col + 4);
      f32x4 ga = *reinterpret_cast<const f32x4*>(wG + row * 128 + col);
      f32x4 gb = *reinterpret_cast<const f32x4*>(wG + row * 128 + col + 4);
      f32x4 ha = *reinterpret_cast<const f32x4*>(wG + row * 128 + 64 + col);
      f32x4 hb = *reinterpret_cast<const f32x4*>(wG + row * 128 + 64 + col + 4);
      #pragma unroll
      for (int j = 0; j < 4; ++j) {
        fWi[m][kk][j]     = (short)f2bf(wa[j]);
        fWi[m][kk][j + 4] = (short)f2bf(wb[j]);
        fD[m][kk][j]      = (short)f2bf(sa[j] - wa[j]);
        fD[m][kk][j + 4]  = (short)f2bf(sb[j] - wb[j]);
        fG1[m][kk][j]     = (short)f2bf(ga[j]);
        fG1[m][kk][j + 4] = (short)f2bf(gb[j]);
        fG2[m][kk][j]     = (short)f2bf(ha[j]);
        fG2[m][kk][j + 4] = (short)f2bf(hb[j]);
      }
    }
  }

  // biases per lane: C/D layout row = m*16 + lg*4 + r
  f32x4 biasA[4], biasG[4];
  #pragma unroll
  for (int m = 0; m < 4; ++m) {
    #pragma unroll
    for (int r = 0; r < 4; ++r) {
      const int ch = m * 16 + lg * 4 + r;
      biasA[m][r] = bS[ch] + 3.f * bI[ch];
      biasG[m][r] = bG[ch];
    }
  }

  __syncthreads();

  const int prow = w * 16 + lr;   // this lane's pixel (tile-local)

  // ---------- xsum B-frag in registers: sum of the 4 tensors' B-frags ----------
  bf16x8 xsB[2];
  #pragma unroll
  for (int kk = 0; kk < 2; ++kk) {
    float acc[8] = {0.f, 0.f, 0.f, 0.f, 0.f, 0.f, 0.f, 0.f};
    #pragma unroll
    for (int i = 0; i < 4; ++i) {
      bf16x8 f = *reinterpret_cast<const bf16x8*>(
          ldsb + i * TILEB + swz(prow, kk * 64 + lg * 16));
      #pragma unroll
      for (int j = 0; j < 8; ++j) acc[j] += bf2f((unsigned short)f[j]);
    }
    #pragma unroll
    for (int j = 0; j < 8; ++j) xsB[kk][j] = (short)f2bf(acc[j]);
  }

  // ---------- Abase = W_inter * xsum + (b_self + 3 b_inter) ----------
  f32x4 Abase[4];
  #pragma unroll
  for (int m = 0; m < 4; ++m) Abase[m] = biasA[m];
  #pragma unroll
  for (int kk = 0; kk < 2; ++kk)
    #pragma unroll
    for (int m = 0; m < 4; ++m)
      Abase[m] = MFMA(fWi[m][kk], xsB[kk], Abase[m]);

  // ---------- per tensor: agg + gate + residual + store ----------
  #pragma unroll
  for (int i = 0; i < 4; ++i) {
    char* tb = ldsb + i * TILEB;

    bf16x8 xB[2];
    #pragma unroll
    for (int kk = 0; kk < 2; ++kk)
      xB[kk] = *reinterpret_cast<const bf16x8*>(tb + swz(prow, kk * 64 + lg * 16));

    // residual pre-read (must precede the agg overwrite of the same bytes)
    u16x4 xr[4];
    #pragma unroll
    for (int m = 0; m < 4; ++m)
      xr[m] = *(const u16x4*)(tb + swz(prow, m * 32 + lg * 8));

    // agg = relu(D * x_i + Abase)
    f32x4 agg[4];
    #pragma unroll
    for (int m = 0; m < 4; ++m) agg[m] = Abase[m];
    #pragma unroll
    for (int kk = 0; kk < 2; ++kk)
      #pragma unroll
      for (int m = 0; m < 4; ++m)
        agg[m] = MFMA(fD[m][kk], xB[kk], agg[m]);

    // pack relu(agg) bf16 into this wave's OWN rows of tile i (intra-wave dep)
    #pragma unroll
    for (int m = 0; m < 4; ++m) {
      u16x4 pk;
      #pragma unroll
      for (int r = 0; r < 4; ++r) pk[r] = f2bf(fmaxf(agg[m][r], 0.f));
      *(u16x4*)(tb + swz(prow, m * 32 + lg * 8)) = pk;
    }
    bf16x8 aB[2];
    #pragma unroll
    for (int kk = 0; kk < 2; ++kk)
      aB[kk] = *reinterpret_cast<const bf16x8*>(tb + swz(prow, kk * 64 + lg * 16));

    // out = x + Wg1*x + Wg2*agg + b_gate
    f32x4 o[4];
    #pragma unroll
    for (int m = 0; m < 4; ++m) o[m] = biasG[m];
    #pragma unroll
    for (int kk = 0; kk < 2; ++kk)
      #pragma unroll
      for (int m = 0; m < 4; ++m) {
        o[m] = MFMA(fG1[m][kk], xB[kk], o[m]);
        o[m] = MFMA(fG2[m][kk], aB[kk], o[m]);
      }

    const int obase = i * 16777216 + b * 64 * HW_ + pimg + prow;
    #pragma unroll
    for (int m = 0; m < 4; ++m) {
      #pragma unroll
      for (int r = 0; r < 4; ++r) {
        const float v = o[m][r] + bf2f(xr[m][r]);
        const int ch = m * 16 + lg * 4 + r;
        out[obase + ch * HW_] = v;
      }
    }
  }
}

extern "C" void kernel_launch(void* const* d_in, const int* in_sizes, int n_in,
                              void* d_out, int out_size, void* d_ws, size_t ws_size,
                              hipStream_t stream) {
  (void)in_sizes; (void)n_in; (void)d_ws; (void)ws_size; (void)out_size;
  gci_kernel<<<dim3(4096), dim3(256), 0, stream>>>(
      (const float*)d_in[0], (const float*)d_in[1],
      (const float*)d_in[2], (const float*)d_in[3],
      (const float*)d_in[4], (const float*)d_in[5],
      (const float*)d_in[6], (const float*)d_in[7],
      (const float*)d_in[8], (const float*)d_in[9],
      (float*)d_out);
}

// Round 7
// 308.924 us; speedup vs baseline: 2.8998x; 2.8998x over previous
//
#include <hip/hip_runtime.h>

typedef __attribute__((ext_vector_type(8))) short bf16x8;
typedef __attribute__((ext_vector_type(4))) float f32x4;
typedef __attribute__((ext_vector_type(4))) unsigned short u16x4;

#define HW_ 16384
#define LDSTR 144     // 72 bf16 elems * 2B per LDS row
#define TILEB 9216    // one 64-pixel x 64-channel bf16 tile

__device__ __forceinline__ float bf2f(unsigned short u) {
  union { unsigned u; float f; } x; x.u = ((unsigned)u) << 16; return x.f;
}
__device__ __forceinline__ unsigned short f2bf(float f) {
  union { float f; unsigned u; } x; x.f = f;
  unsigned r = x.u + 0x7fffu + ((x.u >> 16) & 1u);
  return (unsigned short)(r >> 16);
}
// XOR-swizzled LDS byte offset for transposed tile xT[p][c]
__device__ __forceinline__ int swz(int row, int cb) {
  return row * LDSTR + (cb ^ (((row >> 3) & 7) << 4));
}

#define MFMA(a, b, c) __builtin_amdgcn_mfma_f32_16x16x32_bf16(a, b, c, 0, 0, 0)

// (256,2): do NOT force 4 waves/EU — Round 5 showed that forces VGPR=64 and
// a scratch-spill catastrophe (WRITE_SIZE 268MB->1.79GB). At (256,2) the
// compiler clamps to ~128 VGPR via L2 rematerialization (Round 3: FETCH ideal),
// and LDS=36864 then allows up to 4 blocks/CU.
__global__ __launch_bounds__(256, 2) void gci_kernel(
    const float* __restrict__ x1, const float* __restrict__ x2,
    const float* __restrict__ x3, const float* __restrict__ x4,
    const float* __restrict__ wI, const float* __restrict__ bI,
    const float* __restrict__ wS, const float* __restrict__ bS,
    const float* __restrict__ wG, const float* __restrict__ bG,
    float* __restrict__ out)
{
  // 4 tiles of [64 pixels][72 bf16]: xT0..xT3  (36864 B)
  __shared__ __align__(16) char ldsb[4 * TILEB];

  const int t    = threadIdx.x;
  const int lane = t & 63;
  const int w    = t >> 6;
  const int lr   = lane & 15;
  const int lg   = lane >> 4;

  const int pix0 = blockIdx.x * 64;
  const int b    = pix0 >> 14;          // image index (HW = 16384)
  const int pimg = pix0 & (HW_ - 1);    // pixel offset within image

  const float* xin[4] = {x1, x2, x3, x4};

  // ---------- stage x1..x4 transposed (bf16) into LDS ----------
  #pragma unroll
  for (int ch2 = 0; ch2 < 4; ++ch2) {
    const int q  = ch2 * 256 + t;       // 1024 chunks: 64 channels x 16 pixel-quads
    const int c  = q >> 4;
    const int p4 = q & 15;
    const int goff = (b * 64 + c) * HW_ + pimg + p4 * 4;
    #pragma unroll
    for (int i = 0; i < 4; ++i) {
      f32x4 v = *reinterpret_cast<const f32x4*>(xin[i] + goff);
      #pragma unroll
      for (int j = 0; j < 4; ++j)
        *(unsigned short*)(ldsb + i * TILEB + swz(p4 * 4 + j, c * 2)) = f2bf(v[j]);
    }
  }

  // ---------- per-wave weight A-fragments (fp32 global -> bf16 frags) ----------
  // A-frag(m,kk): lane holds W[m*16 + (l&15)][kk*32 + (l>>4)*8 + j], j=0..7
  bf16x8 fWi[4][2], fD[4][2], fG1[4][2], fG2[4][2];
  #pragma unroll
  for (int m = 0; m < 4; ++m) {
    #pragma unroll
    for (int kk = 0; kk < 2; ++kk) {
      const int row = m * 16 + lr, col = kk * 32 + lg * 8;
      f32x4 wa = *reinterpret_cast<const f32x4*>(wI + row * 64 + col);
      f32x4 wb = *reinterpret_cast<const f32x4*>(wI + row * 64 + col + 4);
      f32x4 sa = *reinterpret_cast<const f32x4*>(wS + row * 64 + col);
      f32x4 sb = *reinterpret_cast<const f32x4*>(wS + row * 64 + col + 4);
      f32x4 ga = *reinterpret_cast<const f32x4*>(wG + row * 128 + col);
      f32x4 gb = *reinterpret_cast<const f32x4*>(wG + row * 128 + col + 4);
      f32x4 ha = *reinterpret_cast<const f32x4*>(wG + row * 128 + 64 + col);
      f32x4 hb = *reinterpret_cast<const f32x4*>(wG + row * 128 + 64 + col + 4);
      #pragma unroll
      for (int j = 0; j < 4; ++j) {
        fWi[m][kk][j]     = (short)f2bf(wa[j]);
        fWi[m][kk][j + 4] = (short)f2bf(wb[j]);
        fD[m][kk][j]      = (short)f2bf(sa[j] - wa[j]);
        fD[m][kk][j + 4]  = (short)f2bf(sb[j] - wb[j]);
        fG1[m][kk][j]     = (short)f2bf(ga[j]);
        fG1[m][kk][j + 4] = (short)f2bf(gb[j]);
        fG2[m][kk][j]     = (short)f2bf(ha[j]);
        fG2[m][kk][j + 4] = (short)f2bf(hb[j]);
      }
    }
  }

  // biases per lane: C/D layout row = m*16 + lg*4 + r
  f32x4 biasA[4], biasG[4];
  #pragma unroll
  for (int m = 0; m < 4; ++m) {
    #pragma unroll
    for (int r = 0; r < 4; ++r) {
      const int ch = m * 16 + lg * 4 + r;
      biasA[m][r] = bS[ch] + 3.f * bI[ch];
      biasG[m][r] = bG[ch];
    }
  }

  __syncthreads();

  const int prow = w * 16 + lr;   // this lane's pixel (tile-local)

  // ---------- xsum B-frag in registers: sum of the 4 tensors' B-frags ----------
  bf16x8 xsB[2];
  #pragma unroll
  for (int kk = 0; kk < 2; ++kk) {
    float acc[8] = {0.f, 0.f, 0.f, 0.f, 0.f, 0.f, 0.f, 0.f};
    #pragma unroll
    for (int i = 0; i < 4; ++i) {
      bf16x8 f = *reinterpret_cast<const bf16x8*>(
          ldsb + i * TILEB + swz(prow, kk * 64 + lg * 16));
      #pragma unroll
      for (int j = 0; j < 8; ++j) acc[j] += bf2f((unsigned short)f[j]);
    }
    #pragma unroll
    for (int j = 0; j < 8; ++j) xsB[kk][j] = (short)f2bf(acc[j]);
  }

  // ---------- Abase = W_inter * xsum + (b_self + 3 b_inter) ----------
  f32x4 Abase[4];
  #pragma unroll
  for (int m = 0; m < 4; ++m) Abase[m] = biasA[m];
  #pragma unroll
  for (int kk = 0; kk < 2; ++kk)
    #pragma unroll
    for (int m = 0; m < 4; ++m)
      Abase[m] = MFMA(fWi[m][kk], xsB[kk], Abase[m]);

  // ---------- per tensor: agg + gate + residual + store ----------
  #pragma unroll
  for (int i = 0; i < 4; ++i) {
    char* tb = ldsb + i * TILEB;

    bf16x8 xB[2];
    #pragma unroll
    for (int kk = 0; kk < 2; ++kk)
      xB[kk] = *reinterpret_cast<const bf16x8*>(tb + swz(prow, kk * 64 + lg * 16));

    // residual pre-read (must precede the agg overwrite of the same bytes)
    u16x4 xr[4];
    #pragma unroll
    for (int m = 0; m < 4; ++m)
      xr[m] = *(const u16x4*)(tb + swz(prow, m * 32 + lg * 8));

    // agg = relu(D * x_i + Abase)
    f32x4 agg[4];
    #pragma unroll
    for (int m = 0; m < 4; ++m) agg[m] = Abase[m];
    #pragma unroll
    for (int kk = 0; kk < 2; ++kk)
      #pragma unroll
      for (int m = 0; m < 4; ++m)
        agg[m] = MFMA(fD[m][kk], xB[kk], agg[m]);

    // pack relu(agg) bf16 into this wave's OWN rows of tile i (intra-wave dep)
    #pragma unroll
    for (int m = 0; m < 4; ++m) {
      u16x4 pk;
      #pragma unroll
      for (int r = 0; r < 4; ++r) pk[r] = f2bf(fmaxf(agg[m][r], 0.f));
      *(u16x4*)(tb + swz(prow, m * 32 + lg * 8)) = pk;
    }
    bf16x8 aB[2];
    #pragma unroll
    for (int kk = 0; kk < 2; ++kk)
      aB[kk] = *reinterpret_cast<const bf16x8*>(tb + swz(prow, kk * 64 + lg * 16));

    // out = x + Wg1*x + Wg2*agg + b_gate
    f32x4 o[4];
    #pragma unroll
    for (int m = 0; m < 4; ++m) o[m] = biasG[m];
    #pragma unroll
    for (int kk = 0; kk < 2; ++kk)
      #pragma unroll
      for (int m = 0; m < 4; ++m) {
        o[m] = MFMA(fG1[m][kk], xB[kk], o[m]);
        o[m] = MFMA(fG2[m][kk], aB[kk], o[m]);
      }

    const int obase = i * 16777216 + b * 64 * HW_ + pimg + prow;
    #pragma unroll
    for (int m = 0; m < 4; ++m) {
      #pragma unroll
      for (int r = 0; r < 4; ++r) {
        const float v = o[m][r] + bf2f(xr[m][r]);
        const int ch = m * 16 + lg * 4 + r;
        out[obase + ch * HW_] = v;
      }
    }
  }
}

extern "C" void kernel_launch(void* const* d_in, const int* in_sizes, int n_in,
                              void* d_out, int out_size, void* d_ws, size_t ws_size,
                              hipStream_t stream) {
  (void)in_sizes; (void)n_in; (void)d_ws; (void)ws_size; (void)out_size;
  gci_kernel<<<dim3(4096), dim3(256), 0, stream>>>(
      (const float*)d_in[0], (const float*)d_in[1],
      (const float*)d_in[2], (const float*)d_in[3],
      (const float*)d_in[4], (const float*)d_in[5],
      (const float*)d_in[6], (const float*)d_in[7],
      (const float*)d_in[8], (const float*)d_in[9],
      (float*)d_out);
}

// Round 8
// 128.030 us; speedup vs baseline: 6.9970x; 2.4129x over previous
//
#include <hip/hip_runtime.h>

typedef __attribute__((ext_vector_type(8))) short bf16x8;
typedef __attribute__((ext_vector_type(4))) float f32x4;
typedef __attribute__((ext_vector_type(4))) unsigned short u16x4;

#define HW_ 16384
#define LDSTR 144     // 72 bf16 elems * 2B per LDS row
#define TILEB 9216    // one 64-pixel x 64-channel bf16 tile

__device__ __forceinline__ float bf2f(unsigned short u) {
  union { unsigned u; float f; } x; x.u = ((unsigned)u) << 16; return x.f;
}
__device__ __forceinline__ unsigned short f2bf(float f) {
  union { float f; unsigned u; } x; x.f = f;
  unsigned r = x.u + 0x7fffu + ((x.u >> 16) & 1u);
  return (unsigned short)(r >> 16);
}
// XOR-swizzled LDS byte offset for transposed tile xT[px][ch]
__device__ __forceinline__ int swz(int row, int cb) {
  return row * LDSTR + (cb ^ (((row >> 3) & 7) << 4));
}

#define MFMA(a, b, c) __builtin_amdgcn_mfma_f32_16x16x32_bf16(a, b, c, 0, 0, 0)

// (256,3): cap = 170 unified VGPR+AGPR per wave -> 3 waves/SIMD.
// Demand after channel-split is ~130-150 (weights now 32 regs/wave, not 128),
// so no spill expected. (256,4) [cap 128] caused the R5 spill disaster;
// (256,2) [cap 256] let the compiler sit at 256 unified = 21% occupancy (R7).
__global__ __launch_bounds__(256, 3) void gci_kernel(
    const float* __restrict__ x1, const float* __restrict__ x2,
    const float* __restrict__ x3, const float* __restrict__ x4,
    const float* __restrict__ wI, const float* __restrict__ bI,
    const float* __restrict__ wS, const float* __restrict__ bS,
    const float* __restrict__ wG, const float* __restrict__ bG,
    float* __restrict__ out)
{
  // 4 tiles of [64 px][72 bf16]: xT0..xT3 (36864 B)
  __shared__ __align__(16) char ldsb[4 * TILEB];

  const int t    = threadIdx.x;
  const int lane = t & 63;
  const int w    = t >> 6;       // wave id == output-channel group (16 ch)
  const int lr   = lane & 15;
  const int lg   = lane >> 4;

  const int pix0 = blockIdx.x * 64;
  const int b    = pix0 >> 14;          // image index (HW = 16384)
  const int pimg = pix0 & (HW_ - 1);    // pixel offset within image

  const float* xin[4] = {x1, x2, x3, x4};

  // ---------- stage x1..x4 transposed (bf16) into LDS ----------
  #pragma unroll
  for (int ch2 = 0; ch2 < 4; ++ch2) {
    const int q  = ch2 * 256 + t;       // 1024 chunks: 64 ch x 16 px-quads
    const int c  = q >> 4;
    const int p4 = q & 15;
    const int goff = (b * 64 + c) * HW_ + pimg + p4 * 4;
    #pragma unroll
    for (int i = 0; i < 4; ++i) {
      f32x4 v = *reinterpret_cast<const f32x4*>(xin[i] + goff);
      #pragma unroll
      for (int j = 0; j < 4; ++j)
        *(unsigned short*)(ldsb + i * TILEB + swz(p4 * 4 + j, c * 2)) = f2bf(v[j]);
    }
  }

  // ---------- this wave's weights: 16 output channels (rows w*16..+15) ----------
  // A-frag(kk): lane holds W[w*16 + lr][kk*32 + lg*8 + j], j=0..7
  bf16x8 fWi[2], fD[2], fG1[2], fG2[2];
  #pragma unroll
  for (int kk = 0; kk < 2; ++kk) {
    const int row = w * 16 + lr, col = kk * 32 + lg * 8;
    f32x4 wa = *(const f32x4*)(wI + row * 64 + col);
    f32x4 wb = *(const f32x4*)(wI + row * 64 + col + 4);
    f32x4 sa = *(const f32x4*)(wS + row * 64 + col);
    f32x4 sb = *(const f32x4*)(wS + row * 64 + col + 4);
    f32x4 ga = *(const f32x4*)(wG + row * 128 + col);
    f32x4 gb = *(const f32x4*)(wG + row * 128 + col + 4);
    f32x4 ha = *(const f32x4*)(wG + row * 128 + 64 + col);
    f32x4 hb = *(const f32x4*)(wG + row * 128 + 64 + col + 4);
    #pragma unroll
    for (int j = 0; j < 4; ++j) {
      fWi[kk][j]     = (short)f2bf(wa[j]);
      fWi[kk][j + 4] = (short)f2bf(wb[j]);
      fD[kk][j]      = (short)f2bf(sa[j] - wa[j]);
      fD[kk][j + 4]  = (short)f2bf(sb[j] - wb[j]);
      fG1[kk][j]     = (short)f2bf(ga[j]);
      fG1[kk][j + 4] = (short)f2bf(gb[j]);
      fG2[kk][j]     = (short)f2bf(ha[j]);
      fG2[kk][j + 4] = (short)f2bf(hb[j]);
    }
  }

  // biases: C/D row = lg*4 + r  ->  ch = w*16 + lg*4 + r
  f32x4 biasA0, biasG;
  #pragma unroll
  for (int r = 0; r < 4; ++r) {
    const int ch = w * 16 + lg * 4 + r;
    biasA0[r] = bS[ch] + 3.f * bI[ch];
    biasG[r]  = bG[ch];
  }

  __syncthreads();

  // ---------- Abase[g] = W_inter * xsum + bias, all 4 px-groups ----------
  f32x4 Abase[4];
  #pragma unroll
  for (int g = 0; g < 4; ++g) {
    bf16x8 xs[2];
    #pragma unroll
    for (int kk = 0; kk < 2; ++kk) {
      float acc[8] = {0.f, 0.f, 0.f, 0.f, 0.f, 0.f, 0.f, 0.f};
      #pragma unroll
      for (int i = 0; i < 4; ++i) {
        bf16x8 f = *(const bf16x8*)(ldsb + i * TILEB + swz(g * 16 + lr, kk * 64 + lg * 16));
        #pragma unroll
        for (int j = 0; j < 8; ++j) acc[j] += bf2f((unsigned short)f[j]);
      }
      #pragma unroll
      for (int j = 0; j < 8; ++j) xs[kk][j] = (short)f2bf(acc[j]);
    }
    Abase[g] = biasA0;
    #pragma unroll
    for (int kk = 0; kk < 2; ++kk) Abase[g] = MFMA(fWi[kk], xs[kk], Abase[g]);
  }

  // ---------- per tensor ----------
  #pragma unroll
  for (int i = 0; i < 4; ++i) {
    char* tb = ldsb + i * TILEB;

    // B-frags for all 4 px-groups (held across agg AND gate; tile is overwritten)
    bf16x8 xB[4][2];
    #pragma unroll
    for (int g = 0; g < 4; ++g)
      #pragma unroll
      for (int kk = 0; kk < 2; ++kk)
        xB[g][kk] = *(const bf16x8*)(tb + swz(g * 16 + lr, kk * 64 + lg * 16));

    // residual pre-read: lane = px, channels (w*16+2j, w*16+2j+1)
    unsigned xrp[8];
    #pragma unroll
    for (int j = 0; j < 8; ++j)
      xrp[j] = *(const unsigned*)(tb + swz(lane, w * 32 + 4 * j));

    // agg = relu(D * x_i + Abase)
    f32x4 agg[4];
    #pragma unroll
    for (int g = 0; g < 4; ++g) {
      agg[g] = Abase[g];
      #pragma unroll
      for (int kk = 0; kk < 2; ++kk) agg[g] = MFMA(fD[kk], xB[g][kk], agg[g]);
    }

    __syncthreads();   // all waves done reading x-tile i

    // write relu(agg) bf16 over tile i: our 16 ch columns, all px rows
    #pragma unroll
    for (int g = 0; g < 4; ++g) {
      u16x4 pk;
      #pragma unroll
      for (int r = 0; r < 4; ++r) pk[r] = f2bf(fmaxf(agg[g][r], 0.f));
      *(u16x4*)(tb + swz(g * 16 + lr, w * 32 + lg * 8)) = pk;
    }

    __syncthreads();   // aggT complete (all 64 channels)

    // gate: out = x + Wg1*x + Wg2*agg + b_gate
    f32x4 og[4];
    #pragma unroll
    for (int g = 0; g < 4; ++g) {
      bf16x8 aB[2];
      #pragma unroll
      for (int kk = 0; kk < 2; ++kk)
        aB[kk] = *(const bf16x8*)(tb + swz(g * 16 + lr, kk * 64 + lg * 16));
      og[g] = biasG;
      #pragma unroll
      for (int kk = 0; kk < 2; ++kk) {
        og[g] = MFMA(fG1[kk], xB[g][kk], og[g]);
        og[g] = MFMA(fG2[kk], aB[kk], og[g]);
      }
    }

    // stores: redistribute so one instruction = 64 consecutive px (256 B lines)
    const int obase0 = i * 16777216 + b * 64 * HW_ + pimg;
    #pragma unroll
    for (int c = 0; c < 16; ++c) {
      const int r    = c & 3;
      const int srcl = ((c >> 2) << 4) | lr;   // lg group holding channel c
      float t0 = __shfl(og[0][r], srcl, 64);
      float t1 = __shfl(og[1][r], srcl, 64);
      float t2 = __shfl(og[2][r], srcl, 64);
      float t3 = __shfl(og[3][r], srcl, 64);
      float v = (lane < 16) ? t0 : (lane < 32) ? t1 : (lane < 48) ? t2 : t3;
      v += bf2f((unsigned short)(xrp[c >> 1] >> ((c & 1) * 16)));
      out[obase0 + (w * 16 + c) * HW_ + lane] = v;
    }
  }
}

extern "C" void kernel_launch(void* const* d_in, const int* in_sizes, int n_in,
                              void* d_out, int out_size, void* d_ws, size_t ws_size,
                              hipStream_t stream) {
  (void)in_sizes; (void)n_in; (void)d_ws; (void)ws_size; (void)out_size;
  gci_kernel<<<dim3(4096), dim3(256), 0, stream>>>(
      (const float*)d_in[0], (const float*)d_in[1],
      (const float*)d_in[2], (const float*)d_in[3],
      (const float*)d_in[4], (const float*)d_in[5],
      (const float*)d_in[6], (const float*)d_in[7],
      (const float*)d_in[8], (const float*)d_in[9],
      (float*)d_out);
}